// Round 9
// baseline (2207.242 us; speedup 1.0000x reference)
//
#include <hip/hip_runtime.h>

#define NN 50000
#define NE 600000
#define IND 64
#define HID 128
#define NREL 10
#define NLAY 6
#define NG 64
#define LN_EPS 1e-5f
#define NSEG (NN * NREL)  // 500000 (node,rel) segments

typedef __attribute__((ext_vector_type(8))) short bf8;
typedef __attribute__((ext_vector_type(4))) float f4;

__device__ __forceinline__ ushort f2bf(float x) {
  uint u = __float_as_uint(x);
  u += 0x7fff + ((u >> 16) & 1);
  return (ushort)(u >> 16);
}
__device__ __forceinline__ float bf2f(ushort h) {
  return __uint_as_float(((uint)h) << 16);
}

// ---------------------------------------------------------------- utilities
__global__ void zero_kernel(float* __restrict__ p, int n) {
  int i = blockIdx.x * blockDim.x + threadIdx.x;
  int stride = gridDim.x * blockDim.x;
  for (; i < n; i += stride) p[i] = 0.f;
}

__global__ void count_edges2(const int* __restrict__ dst, const int* __restrict__ et,
                             int* __restrict__ cnt2) {
  int e = blockIdx.x * 256 + threadIdx.x;
  if (e >= NE) return;
  atomicAdd(&cnt2[dst[e] * NREL + et[e]], 1);
}

__global__ void invert_winv2(const int* __restrict__ cnt2, float* __restrict__ winv) {
  int i = blockIdx.x * 256 + threadIdx.x;
  if (i < NSEG) winv[i] = 1.0f / (float)max(cnt2[i], 1);
}

__global__ void scan_block(const int* __restrict__ src, int* __restrict__ excl,
                           int* __restrict__ partial, int n) {
  __shared__ int sh[256];
  int i = blockIdx.x * 256 + threadIdx.x;
  int v = (i < n) ? src[i] : 0;
  sh[threadIdx.x] = v;
  __syncthreads();
  int x = v;
  for (int off = 1; off < 256; off <<= 1) {
    int y = (threadIdx.x >= off) ? sh[threadIdx.x - off] : 0;
    __syncthreads();
    x += y;
    sh[threadIdx.x] = x;
    __syncthreads();
  }
  if (i < n) excl[i] = x - v;
  if (threadIdx.x == 255) partial[blockIdx.x] = x;
}

__global__ void scan_partials_big(int* __restrict__ partial, int nb) {
  __shared__ int sh[256];
  __shared__ int runsh;
  if (threadIdx.x == 0) runsh = 0;
  __syncthreads();
  int nch = (nb + 255) / 256;
  for (int c = 0; c < nch; ++c) {
    int i = c * 256 + threadIdx.x;
    int v = (i < nb) ? partial[i] : 0;
    sh[threadIdx.x] = v;
    __syncthreads();
    int x = v;
    for (int off = 1; off < 256; off <<= 1) {
      int y = (threadIdx.x >= off) ? sh[threadIdx.x - off] : 0;
      __syncthreads();
      x += y;
      sh[threadIdx.x] = x;
      __syncthreads();
    }
    int run = runsh;
    if (i < nb) partial[i] = run + x - v;
    __syncthreads();
    if (threadIdx.x == 255) runsh = run + x;
    __syncthreads();
  }
}

__global__ void scan_add(int* __restrict__ excl, const int* __restrict__ partial, int n,
                         int total) {
  int i = blockIdx.x * 256 + threadIdx.x;
  if (i < n) excl[i] += partial[i >> 8];
  if (i == 0) excl[n] = total;
}

__global__ void fill_csr2(const int* __restrict__ dst, const int* __restrict__ src,
                          const int* __restrict__ et, int* __restrict__ fp2,
                          const int* __restrict__ rs2, int* __restrict__ eidx) {
  int e = blockIdx.x * 256 + threadIdx.x;
  if (e >= NE) return;
  int seg = dst[e] * NREL + et[e];
  int pos = rs2[seg] + atomicAdd(&fp2[seg], 1);
  eidx[pos] = src[e];
}

// ------------------------------------------------------------- weight prep
__global__ void transpose_split_frag(const float* __restrict__ src, ushort* __restrict__ dh,
                                     ushort* __restrict__ dl, int K) {
  int i = blockIdx.x * 256 + threadIdx.x;
  int tot = K * 128;
  if (i >= tot) return;
  int k = i / 128;
  int n = i - k * 128;
  float v = src[i];
  ushort h = f2bf(v);
  size_t o = (size_t)(n >> 4) * (K * 16) + (k >> 3) * 128 + (n & 15) * 8 + (k & 7);
  dh[o] = h;
  dl[o] = f2bf(v - bf2f(h));
}

// Pack per-layer big-B (K=1536): B1=[root_h; root_h; W1_h..W10_h], B2=[root_l; 0; W_l]
__global__ void pack_B(const float* __restrict__ root_w, const float* __restrict__ rel_w,
                       ushort* __restrict__ Bp) {
  int i = blockIdx.x * 256 + threadIdx.x;
  const int tot = NLAY * 1536 * 128;
  if (i >= tot) return;
  int l = i / (1536 * 128);
  int rem = i - l * (1536 * 128);
  int k = rem >> 7;
  int n = rem & 127;
  ushort s1, s2;
  if (k < 128) {
    float v = root_w[(size_t)l * 16384 + k * 128 + n];
    s1 = f2bf(v);
    s2 = f2bf(v - bf2f(s1));
  } else if (k < 256) {
    float v = root_w[(size_t)l * 16384 + (k - 128) * 128 + n];
    s1 = f2bf(v);
    s2 = 0;
  } else {
    int r = (k - 256) >> 7, kk = (k - 256) & 127;
    float v = rel_w[(((size_t)l * NREL + r) * 128 + kk) * 128 + n];
    s1 = f2bf(v);
    s2 = f2bf(v - bf2f(s1));
  }
  size_t off = (size_t)(n >> 4) * 24576 + (k >> 3) * 128 + (n & 15) * 8 + (k & 7);
  size_t base = (size_t)l * 2 * 196608;
  Bp[base + off] = s1;
  Bp[base + 196608 + off] = s2;
}

// rows fp32 [N][K] -> fragment-linear bf16 hi/lo (+optional linear bf16 copy)
template <int K>
__global__ __launch_bounds__(256) void split_frag(const float* __restrict__ src,
                                                  ushort* __restrict__ dh,
                                                  ushort* __restrict__ dl,
                                                  ushort* __restrict__ db) {
  constexpr int TOT = 16 * K;
  __shared__ ushort sh[TOT], sl[TOT];
  int grp = blockIdx.x;
  const float* s = src + (size_t)grp * TOT;
  for (int i = threadIdx.x * 4; i < TOT; i += 1024) {
    float4 v = *(const float4*)(s + i);
    int nl = i / K, d = i - nl * K;
    int off = (d >> 3) * 128 + nl * 8 + (d & 7);
    ushort h0 = f2bf(v.x), h1 = f2bf(v.y), h2 = f2bf(v.z), h3 = f2bf(v.w);
    *(uint*)(sh + off) = (uint)h0 | ((uint)h1 << 16);
    *(uint*)(sh + off + 2) = (uint)h2 | ((uint)h3 << 16);
    *(uint*)(sl + off) = (uint)f2bf(v.x - bf2f(h0)) | ((uint)f2bf(v.y - bf2f(h1)) << 16);
    *(uint*)(sl + off + 2) = (uint)f2bf(v.z - bf2f(h2)) | ((uint)f2bf(v.w - bf2f(h3)) << 16);
    if (db) {
      uint2 pk;
      pk.x = (uint)h0 | ((uint)h1 << 16);
      pk.y = (uint)h2 | ((uint)h3 << 16);
      *(uint2*)(db + (size_t)(grp * 16 + nl) * K + d) = pk;
    }
  }
  __syncthreads();
  size_t base = (size_t)grp * TOT;
  for (int i = threadIdx.x * 8; i < TOT; i += 2048) {
    *(bf8*)(dh + base + i) = *(const bf8*)(sh + i);
    *(bf8*)(dl + base + i) = *(const bf8*)(sl + i);
  }
}

// ------------------------------------------- projection GEMM (3-term, K=64)
struct Frags {
  bf8 ah[4], al[4], bh[4], bl[4];
};

template <int K>
__device__ __forceinline__ void load_frags(Frags& f, int ks, const ushort* Abh,
                                           const ushort* Abl, const ushort* Bbh,
                                           const ushort* Bbl) {
#pragma unroll
  for (int m = 0; m < 4; ++m) {
    f.ah[m] = *(const bf8*)(Abh + (size_t)m * (K * 16) + ks * 512);
    f.al[m] = *(const bf8*)(Abl + (size_t)m * (K * 16) + ks * 512);
  }
#pragma unroll
  for (int n = 0; n < 4; ++n) {
    f.bh[n] = *(const bf8*)(Bbh + (size_t)n * (K * 16) + ks * 512);
    f.bl[n] = *(const bf8*)(Bbl + (size_t)n * (K * 16) + ks * 512);
  }
}

__device__ __forceinline__ void mfma_frags(f4 (&acc)[4][4], const Frags& f) {
#pragma unroll
  for (int m = 0; m < 4; ++m)
#pragma unroll
    for (int n = 0; n < 4; ++n) {
      acc[m][n] = __builtin_amdgcn_mfma_f32_16x16x32_bf16(f.ah[m], f.bh[n], acc[m][n], 0, 0, 0);
      acc[m][n] = __builtin_amdgcn_mfma_f32_16x16x32_bf16(f.al[m], f.bh[n], acc[m][n], 0, 0, 0);
      acc[m][n] = __builtin_amdgcn_mfma_f32_16x16x32_bf16(f.ah[m], f.bl[n], acc[m][n], 0, 0, 0);
    }
}

template <int K>
__global__ __launch_bounds__(256) void gemm_frag(
    const ushort* __restrict__ Ah, const ushort* __restrict__ Al,
    const ushort* __restrict__ Bh, const ushort* __restrict__ Bl,
    const float* __restrict__ bias, float* __restrict__ Cf, int M) {
  const int bm = blockIdx.y * 128;
  const int tid = threadIdx.x, w = tid >> 6, lane = tid & 63;
  const int wr = (w >> 1) * 64, wc = (w & 1) * 64;
  const int lr = lane & 15;

  const ushort* Abh = Ah + ((size_t)(bm >> 4) + (wr >> 4)) * (K * 16) + lane * 8;
  const ushort* Abl = Al + ((size_t)(bm >> 4) + (wr >> 4)) * (K * 16) + lane * 8;
  const ushort* Bbh = Bh + (size_t)(wc >> 4) * (K * 16) + lane * 8;
  const ushort* Bbl = Bl + (size_t)(wc >> 4) * (K * 16) + lane * 8;

  f4 acc[4][4] = {};
  Frags fa, fb;
  load_frags<K>(fa, 0, Abh, Abl, Bbh, Bbl);
  load_frags<K>(fb, 1, Abh, Abl, Bbh, Bbl);
  mfma_frags(acc, fa);
  mfma_frags(acc, fb);

  const int rgrp = (lane >> 4) * 4;
#pragma unroll
  for (int n = 0; n < 4; ++n) {
    int col = wc + n * 16 + lr;
    float bv = bias[col];
#pragma unroll
    for (int m = 0; m < 4; ++m) {
      int r0 = bm + wr + m * 16 + rgrp;
#pragma unroll
      for (int j = 0; j < 4; ++j) {
        int r = r0 + j;
        if (r < M) Cf[(size_t)r * 128 + col] = acc[m][n][j] + bv;
      }
    }
  }
}

// ------------------------- fused per-layer: aggregate (LDS) + big-K GEMM
// OUT = [hh | hl | AGG(on the fly)] @ (B1 + B2) + bias.
// Block = 128 nodes. LDS A-tile holds 2 relations (K=256 chunk), 5 chunks.
// Aggregation: flat edge walk per (node, rel-pair); relation of edge p is
// (p >= mid) -- arithmetic, no memory, no predicated fan-out. U=8 MLP gathers.
__device__ __forceinline__ void g2h(f4 (&acc)[4][4], const ushort* A, int c,
                                    const ushort* B1, const ushort* B2, int cb,
                                    bool useB2) {
  bf8 a[4], b1[4], b2[4];
#pragma unroll
  for (int m = 0; m < 4; ++m) a[m] = *(const bf8*)(A + (size_t)m * 2048 + c * 512);
#pragma unroll
  for (int n = 0; n < 4; ++n) {
    b1[n] = *(const bf8*)(B1 + (size_t)n * 24576 + (size_t)cb * 512);
    if (useB2) b2[n] = *(const bf8*)(B2 + (size_t)n * 24576 + (size_t)cb * 512);
  }
#pragma unroll
  for (int m = 0; m < 4; ++m)
#pragma unroll
    for (int n = 0; n < 4; ++n) {
      acc[m][n] = __builtin_amdgcn_mfma_f32_16x16x32_bf16(a[m], b1[n], acc[m][n], 0, 0, 0);
      if (useB2)
        acc[m][n] = __builtin_amdgcn_mfma_f32_16x16x32_bf16(a[m], b2[n], acc[m][n], 0, 0, 0);
    }
}

__global__ __launch_bounds__(256) void fused_layer(
    const ushort* __restrict__ hh, const ushort* __restrict__ hl,
    const int* __restrict__ rs2, const int* __restrict__ eidx,
    const float* __restrict__ winv, const ushort* __restrict__ hb,
    const ushort* __restrict__ Bp, const float* __restrict__ bias,
    float* __restrict__ OUT, int M) {
  __shared__ ushort st[128][264];  // [node-in-block][k within 2-rel chunk], +8 pad
  const int bm = blockIdx.x * 128;
  const int tid = threadIdx.x, w = tid >> 6, lane = tid & 63;
  const int wr = (w >> 1) * 64, wc = (w & 1) * 64;
  const int lr = lane & 15;
  const int ag = (bm >> 4) + (wr >> 4);

  const ushort* pH = hh + (size_t)ag * 2048 + lane * 8;
  const ushort* pL = hl + (size_t)ag * 2048 + lane * 8;
  const ushort* pB1 = Bp + (size_t)(wc >> 4) * 24576 + lane * 8;
  const ushort* pB2 = pB1 + 196608;
  const ushort* hbl = hb + lane * 2;

  f4 acc[4][4] = {};

  auto agg_chunk = [&](int c) {
    const int r0 = 2 * c;
    for (int i = 0; i < 32; ++i) {
      int irow = w * 32 + i;
      int node = bm + irow;
      float ax0 = 0.f, ay0 = 0.f, ax1 = 0.f, ay1 = 0.f;
      float w0 = 0.f, w1 = 0.f;
      if (node < M) {
        int base = node * NREL + r0;
        int e0 = rs2[base];
        int mid = rs2[base + 1];
        int e2 = rs2[base + 2];
        w0 = winv[base];
        w1 = winv[base + 1];
        int p = e0;
        for (; p + 8 <= e2; p += 8) {
          int s[8];
          uint v[8];
#pragma unroll
          for (int u = 0; u < 8; ++u) s[u] = eidx[p + u];
#pragma unroll
          for (int u = 0; u < 8; ++u) v[u] = *(const uint*)(hbl + (size_t)s[u] * HID);
#pragma unroll
          for (int u = 0; u < 8; ++u) {
            float vx = __uint_as_float(v[u] << 16);
            float vy = __uint_as_float(v[u] & 0xffff0000u);
            bool sec = (p + u >= mid);
            float tx = sec ? 0.f : vx, ty = sec ? 0.f : vy;
            ax0 += tx;
            ay0 += ty;
            ax1 += vx - tx;
            ay1 += vy - ty;
          }
        }
        for (; p < e2; ++p) {
          uint v = *(const uint*)(hbl + (size_t)eidx[p] * HID);
          float vx = __uint_as_float(v << 16);
          float vy = __uint_as_float(v & 0xffff0000u);
          bool sec = (p >= mid);
          float tx = sec ? 0.f : vx, ty = sec ? 0.f : vy;
          ax0 += tx;
          ay0 += ty;
          ax1 += vx - tx;
          ay1 += vy - ty;
        }
      }
      *(uint*)&st[irow][lane * 2] = (uint)f2bf(ax0 * w0) | ((uint)f2bf(ay0 * w0) << 16);
      *(uint*)&st[irow][128 + lane * 2] =
          (uint)f2bf(ax1 * w1) | ((uint)f2bf(ay1 * w1) << 16);
    }
  };

  auto mfma_chunk = [&](int c) {
#pragma unroll
    for (int ks = 0; ks < 8; ++ks) {
      bf8 a[4], b1[4], b2[4];
      int cb = 8 + c * 8 + ks;
#pragma unroll
      for (int m = 0; m < 4; ++m)
        a[m] = *(const bf8*)&st[wr + m * 16 + lr][ks * 32 + (lane >> 4) * 8];
#pragma unroll
      for (int n = 0; n < 4; ++n) {
        b1[n] = *(const bf8*)(pB1 + (size_t)n * 24576 + (size_t)cb * 512);
        b2[n] = *(const bf8*)(pB2 + (size_t)n * 24576 + (size_t)cb * 512);
      }
#pragma unroll
      for (int m = 0; m < 4; ++m)
#pragma unroll
        for (int n = 0; n < 4; ++n) {
          acc[m][n] = __builtin_amdgcn_mfma_f32_16x16x32_bf16(a[m], b1[n], acc[m][n], 0, 0, 0);
          acc[m][n] = __builtin_amdgcn_mfma_f32_16x16x32_bf16(a[m], b2[n], acc[m][n], 0, 0, 0);
        }
    }
  };

  // chunk 0 aggregation first (gathers in flight), then the h-part MFMAs
  agg_chunk(0);
#pragma unroll
  for (int c = 0; c < 4; ++c) g2h(acc, pH, c, pB1, pB2, c, true);
#pragma unroll
  for (int c = 0; c < 4; ++c) g2h(acc, pL, c, pB1, pB2, 4 + c, false);
  __syncthreads();

  for (int c = 0; c < 5; ++c) {
    mfma_chunk(c);
    __syncthreads();
    if (c < 4) {
      agg_chunk(c + 1);
      __syncthreads();
    }
  }

  const int rgrp = (lane >> 4) * 4;
#pragma unroll
  for (int n = 0; n < 4; ++n) {
    int col = wc + n * 16 + lr;
    float bv = bias[col];
#pragma unroll
    for (int m = 0; m < 4; ++m) {
      int r0 = bm + wr + m * 16 + rgrp;
#pragma unroll
      for (int j = 0; j < 4; ++j) {
        int r = r0 + j;
        if (r < M) OUT[(size_t)r * 128 + col] = acc[m][n][j] + bv;
      }
    }
  }
}

// ------------------- LN + ReLU + residual (+ bf16 split + linear bf16 copy)
__global__ __launch_bounds__(256) void ln2(
    const float* __restrict__ OUT, float* __restrict__ h,
    const float* __restrict__ g, const float* __restrict__ b,
    ushort* __restrict__ dh, ushort* __restrict__ dl, ushort* __restrict__ db,
    int writeSplit) {
  __shared__ ushort sh[2048], sl[2048];
  int grp = blockIdx.x;
  int w = threadIdx.x >> 6, lane = threadIdx.x & 63;
  int lo = lane * 2;
  float2 gg = *(const float2*)(g + lo);
  float2 bb = *(const float2*)(b + lo);
#pragma unroll
  for (int p = 0; p < 4; ++p) {
    int r = w * 4 + p;
    int node = grp * 16 + r;
    float2 v = *(const float2*)(OUT + (size_t)node * HID + lo);
    float s = v.x + v.y, sq = v.x * v.x + v.y * v.y;
#pragma unroll
    for (int off = 32; off; off >>= 1) {
      s += __shfl_xor(s, off);
      sq += __shfl_xor(sq, off);
    }
    float mu = s * (1.f / HID);
    float var = sq * (1.f / HID) - mu * mu;
    float rs = rsqrtf(var + LN_EPS);
    float2 rr = *(const float2*)(h + (size_t)node * HID + lo);
    float y0 = fmaxf((v.x - mu) * rs * gg.x + bb.x, 0.f) + rr.x;
    float y1 = fmaxf((v.y - mu) * rs * gg.y + bb.y, 0.f) + rr.y;
    *(float2*)(h + (size_t)node * HID + lo) = make_float2(y0, y1);
    if (writeSplit) {
      ushort h0 = f2bf(y0), h1 = f2bf(y1);
      int off2 = (lo >> 3) * 128 + r * 8 + (lo & 7);
      *(uint*)(sh + off2) = (uint)h0 | ((uint)h1 << 16);
      *(uint*)(sl + off2) = (uint)f2bf(y0 - bf2f(h0)) | ((uint)f2bf(y1 - bf2f(h1)) << 16);
      *(uint*)(db + (size_t)node * HID + lo) = (uint)h0 | ((uint)h1 << 16);
    }
  }
  __syncthreads();
  if (writeSplit) {
    size_t base = (size_t)grp * 2048;
    int t8 = threadIdx.x * 8;
    *(bf8*)(dh + base + t8) = *(const bf8*)(sh + t8);
    *(bf8*)(dl + base + t8) = *(const bf8*)(sl + t8);
  }
}

// ---------------------------------------------------------------- pooling
__global__ void pool_kernel(const float* __restrict__ h, const int* __restrict__ batch,
                            float* __restrict__ out) {
  int n0 = blockIdx.x * 64;
  if (n0 >= NN) return;
  int t = threadIdx.x;
  int nend = min(n0 + 64, NN);
  int cur = batch[n0];
  float acc = 0.f;
  for (int n = n0; n < nend; ++n) {
    int gph = batch[n];
    if (gph != cur) {
      atomicAdd(&out[cur * HID + t], acc);
      acc = 0.f;
      cur = gph;
    }
    acc += h[(size_t)n * HID + t];
  }
  atomicAdd(&out[cur * HID + t], acc);
}

// ---------------------------------------------------------------- launch
extern "C" void kernel_launch(void* const* d_in, const int* in_sizes, int n_in,
                              void* d_out, int out_size, void* d_ws, size_t ws_size,
                              hipStream_t stream) {
  const float* x = (const float*)d_in[0];
  const int* ei = (const int*)d_in[1];
  const int* et = (const int*)d_in[2];
  const int* batch = (const int*)d_in[3];
  const float* Wp = (const float*)d_in[4];
  const float* bp = (const float*)d_in[5];
  const float* rel_w = (const float*)d_in[6];
  const float* root_w = (const float*)d_in[7];
  const float* conv_b = (const float*)d_in[8];
  const float* ln_g = (const float*)d_in[9];
  const float* ln_b = (const float*)d_in[10];
  float* out = (float*)d_out;
  const int* srcv = ei;
  const int* dstv = ei + NE;

  const int NGRP = NN / 16;       // 3125 exact
  const int NGRP_PAD = NGRP + 3;  // GEMMs read up to group 3127 (stores guarded)

  char* w = (char*)d_ws;
  auto alloc = [&](size_t bytes) {
    char* p = w;
    w += (bytes + 255) & ~(size_t)255;
    return p;
  };
  float* h = (float*)alloc((size_t)NN * HID * 4);
  float* OUT = (float*)alloc((size_t)NN * HID * 4);
  int* cnt2 = (int*)alloc((size_t)NSEG * 4);  // zero-span start
  int* fp2 = (int*)alloc((size_t)NSEG * 4);
  char* zend = w;  // zero-span end
  float* winv = (float*)alloc((size_t)NSEG * 4);
  int* rs2 = (int*)alloc((size_t)(NSEG + 1) * 4);
  int* eidx = (int*)alloc((size_t)NE * 4);
  int* partial = (int*)alloc(2048 * 4);
  ushort* xh = (ushort*)alloc((size_t)NGRP_PAD * 1024 * 2);
  ushort* xl = (ushort*)alloc((size_t)NGRP_PAD * 1024 * 2);
  ushort* hh = (ushort*)alloc((size_t)NGRP_PAD * 2048 * 2);
  ushort* hl = (ushort*)alloc((size_t)NGRP_PAD * 2048 * 2);
  ushort* hb = (ushort*)alloc((size_t)NN * HID * 2);
  ushort* Wph = (ushort*)alloc((size_t)IND * HID * 2);
  ushort* Wpl = (ushort*)alloc((size_t)IND * HID * 2);
  ushort* Bp = (ushort*)alloc((size_t)NLAY * 2 * 196608 * 2);

  const int NB_E = (NE + 255) / 256;
  const int NB_S = (NSEG + 255) / 256;  // 1954
  const int MB = (NN + 127) / 128;      // 391
  const int ZSPAN = (int)((zend - (char*)cnt2) / 4);

  zero_kernel<<<dim3(1024), dim3(256), 0, stream>>>((float*)cnt2, ZSPAN);
  zero_kernel<<<dim3(32), dim3(256), 0, stream>>>(out, NG * HID);

  count_edges2<<<dim3(NB_E), dim3(256), 0, stream>>>(dstv, et, cnt2);
  invert_winv2<<<dim3(NB_S), dim3(256), 0, stream>>>(cnt2, winv);
  scan_block<<<dim3(NB_S), dim3(256), 0, stream>>>(cnt2, rs2, partial, NSEG);
  scan_partials_big<<<dim3(1), dim3(256), 0, stream>>>(partial, NB_S);
  scan_add<<<dim3(NB_S), dim3(256), 0, stream>>>(rs2, partial, NSEG, NE);
  fill_csr2<<<dim3(NB_E), dim3(256), 0, stream>>>(dstv, srcv, et, fp2, rs2, eidx);

  transpose_split_frag<<<dim3((IND * HID + 255) / 256), dim3(256), 0, stream>>>(
      Wp, Wph, Wpl, IND);
  pack_B<<<dim3((NLAY * 1536 * 128 + 255) / 256), dim3(256), 0, stream>>>(
      root_w, rel_w, Bp);

  split_frag<IND><<<dim3(NGRP), dim3(256), 0, stream>>>(x, xh, xl, (ushort*)nullptr);

  // projection: h = x @ Wp + bp (3-term)
  gemm_frag<IND><<<dim3(1, MB), dim3(256), 0, stream>>>(xh, xl, Wph, Wpl, bp, h, NN);
  split_frag<HID><<<dim3(NGRP), dim3(256), 0, stream>>>(h, hh, hl, hb);

  for (int l = 0; l < NLAY; ++l) {
    fused_layer<<<dim3(MB), dim3(256), 0, stream>>>(
        hh, hl, rs2, eidx, winv, hb, Bp + (size_t)l * 2 * 196608,
        conv_b + (size_t)l * HID, OUT, NN);
    ln2<<<dim3(NGRP), dim3(256), 0, stream>>>(
        OUT, h, ln_g + (size_t)l * HID, ln_b + (size_t)l * HID, hh, hl, hb,
        (l != NLAY - 1) ? 1 : 0);
  }

  pool_kernel<<<dim3((NN + 63) / 64), dim3(128), 0, stream>>>(h, batch, out);
}

// Round 10
// 873.296 us; speedup vs baseline: 2.5275x; 2.5275x over previous
//
#include <hip/hip_runtime.h>

#define NN 50000
#define NE 600000
#define IND 64
#define HID 128
#define NREL 10
#define NLAY 6
#define NG 64
#define LN_EPS 1e-5f
#define NMAT 11

typedef __attribute__((ext_vector_type(8))) short bf8;
typedef __attribute__((ext_vector_type(4))) float f4;

__device__ __forceinline__ ushort f2bf(float x) {
  uint u = __float_as_uint(x);
  u += 0x7fff + ((u >> 16) & 1);
  return (ushort)(u >> 16);
}
__device__ __forceinline__ float bf2f(ushort h) {
  return __uint_as_float(((uint)h) << 16);
}

// ---------------------------------------------------------------- utilities
__global__ void zero_kernel(float* __restrict__ p, int n) {
  int i = blockIdx.x * blockDim.x + threadIdx.x;
  int stride = gridDim.x * blockDim.x;
  for (; i < n; i += stride) p[i] = 0.f;
}

__global__ void count_edges(const int* __restrict__ dst, const int* __restrict__ et,
                            float* __restrict__ winv, int* __restrict__ deg) {
  int e = blockIdx.x * 256 + threadIdx.x;
  if (e >= NE) return;
  int d = dst[e];
  atomicAdd(&winv[d * NREL + et[e]], 1.0f);
  atomicAdd(&deg[d], 1);
}

__global__ void invert_winv(float* __restrict__ winv) {
  int i = blockIdx.x * 256 + threadIdx.x;
  if (i < NN * NREL) winv[i] = 1.0f / fmaxf(winv[i], 1.0f);
}

__global__ void scan_block(const int* __restrict__ deg, int* __restrict__ rowstart,
                           int* __restrict__ partial) {
  __shared__ int sh[256];
  int i = blockIdx.x * 256 + threadIdx.x;
  int v = (i < NN) ? deg[i] : 0;
  sh[threadIdx.x] = v;
  __syncthreads();
  int x = v;
  for (int off = 1; off < 256; off <<= 1) {
    int y = (threadIdx.x >= off) ? sh[threadIdx.x - off] : 0;
    __syncthreads();
    x += y;
    sh[threadIdx.x] = x;
    __syncthreads();
  }
  if (i < NN) rowstart[i] = x - v;
  if (threadIdx.x == 255) partial[blockIdx.x] = x;
}

__global__ void scan_partials(int* __restrict__ partial, int nb) {
  __shared__ int sh[256];
  int v = (threadIdx.x < nb) ? partial[threadIdx.x] : 0;
  sh[threadIdx.x] = v;
  __syncthreads();
  int x = v;
  for (int off = 1; off < 256; off <<= 1) {
    int y = (threadIdx.x >= off) ? sh[threadIdx.x - off] : 0;
    __syncthreads();
    x += y;
    sh[threadIdx.x] = x;
    __syncthreads();
  }
  partial[threadIdx.x] = x - v;
}

__global__ void scan_add(int* __restrict__ rowstart, const int* __restrict__ partial) {
  int i = blockIdx.x * 256 + threadIdx.x;
  if (i < NN) rowstart[i] += partial[i >> 8];
  if (i == 0) rowstart[NN] = NE;
}

// CSR fill with precomputed packed (src,type) and per-edge scale winv[dst,type]
__global__ void fill_csr(const int* __restrict__ dst, const int* __restrict__ src,
                         const int* __restrict__ et, int* __restrict__ fillpos,
                         const int* __restrict__ rowstart, const float* __restrict__ winv,
                         int* __restrict__ pkd, float* __restrict__ wsc) {
  int e = blockIdx.x * 256 + threadIdx.x;
  if (e >= NE) return;
  int d = dst[e], t = et[e];
  int pos = rowstart[d] + atomicAdd(&fillpos[d], 1);
  pkd[pos] = (src[e] << 4) | t;
  wsc[pos] = winv[d * NREL + t];
}

// ------------------------------------------------------------- weight prep
__global__ void transpose_split_frag(const float* __restrict__ src, ushort* __restrict__ dh,
                                     ushort* __restrict__ dl, int nmat, int K,
                                     int ddiv, int dmul, int dadd) {
  int i = blockIdx.x * 256 + threadIdx.x;
  int tot = nmat * K * 128;
  if (i >= tot) return;
  int m = i / (K * 128);
  int rem = i - m * (K * 128);
  int k = rem / 128;
  int n = rem - k * 128;
  float v = src[i];
  ushort h = f2bf(v);
  int dm = (m / ddiv) * dmul + (m % ddiv) + dadd;
  size_t o = (size_t)dm * (K * 128) + (size_t)(n >> 4) * (K * 16) + (k >> 3) * 128 +
             (n & 15) * 8 + (k & 7);
  dh[o] = h;
  dl[o] = f2bf(v - bf2f(h));
}

// rows fp32 [N][K] -> fragment-linear bf16 hi/lo
template <int K>
__global__ __launch_bounds__(256) void split_frag(const float* __restrict__ src,
                                                  ushort* __restrict__ dh,
                                                  ushort* __restrict__ dl) {
  constexpr int TOT = 16 * K;
  __shared__ ushort sh[TOT], sl[TOT];
  int grp = blockIdx.x;
  const float* s = src + (size_t)grp * TOT;
  for (int i = threadIdx.x * 4; i < TOT; i += 1024) {
    float4 v = *(const float4*)(s + i);
    int nl = i / K, d = i - nl * K;
    int off = (d >> 3) * 128 + nl * 8 + (d & 7);
    ushort h0 = f2bf(v.x), h1 = f2bf(v.y), h2 = f2bf(v.z), h3 = f2bf(v.w);
    *(uint*)(sh + off) = (uint)h0 | ((uint)h1 << 16);
    *(uint*)(sh + off + 2) = (uint)h2 | ((uint)h3 << 16);
    *(uint*)(sl + off) = (uint)f2bf(v.x - bf2f(h0)) | ((uint)f2bf(v.y - bf2f(h1)) << 16);
    *(uint*)(sl + off + 2) = (uint)f2bf(v.z - bf2f(h2)) | ((uint)f2bf(v.w - bf2f(h3)) << 16);
  }
  __syncthreads();
  size_t base = (size_t)grp * TOT;
  for (int i = threadIdx.x * 8; i < TOT; i += 2048) {
    *(bf8*)(dh + base + i) = *(const bf8*)(sh + i);
    *(bf8*)(dl + base + i) = *(const bf8*)(sl + i);
  }
}

// ----------------------------------------------------- LDS-free bf16 GEMM
// Root/projection blocks (bx==nrel): 3-term fp32-equivalent, fp32 out + bias.
// T blocks (bx<nrel): 1-term (T is bf16-rounded on store anyway), bf16 out
// via half-tile LDS staging (17 KB) for coalesced stores.
struct Frags {
  bf8 ah[4], al[4], bh[4], bl[4];
};

template <int K>
__device__ __forceinline__ void load_frags(Frags& f, int ks, const ushort* Abh,
                                           const ushort* Abl, const ushort* Bbh,
                                           const ushort* Bbl) {
#pragma unroll
  for (int m = 0; m < 4; ++m) {
    f.ah[m] = *(const bf8*)(Abh + (size_t)m * (K * 16) + ks * 512);
    f.al[m] = *(const bf8*)(Abl + (size_t)m * (K * 16) + ks * 512);
  }
#pragma unroll
  for (int n = 0; n < 4; ++n) {
    f.bh[n] = *(const bf8*)(Bbh + (size_t)n * (K * 16) + ks * 512);
    f.bl[n] = *(const bf8*)(Bbl + (size_t)n * (K * 16) + ks * 512);
  }
}

__device__ __forceinline__ void mfma_frags(f4 (&acc)[4][4], const Frags& f) {
#pragma unroll
  for (int m = 0; m < 4; ++m)
#pragma unroll
    for (int n = 0; n < 4; ++n) {
      acc[m][n] = __builtin_amdgcn_mfma_f32_16x16x32_bf16(f.ah[m], f.bh[n], acc[m][n], 0, 0, 0);
      acc[m][n] = __builtin_amdgcn_mfma_f32_16x16x32_bf16(f.al[m], f.bh[n], acc[m][n], 0, 0, 0);
      acc[m][n] = __builtin_amdgcn_mfma_f32_16x16x32_bf16(f.ah[m], f.bl[n], acc[m][n], 0, 0, 0);
    }
}

template <int K>
__global__ __launch_bounds__(256) void gemm_frag(
    const ushort* __restrict__ Ah, const ushort* __restrict__ Al,
    const ushort* __restrict__ Bh, const ushort* __restrict__ Bl,
    const float* __restrict__ bias, float* __restrict__ Cf, ushort* __restrict__ Cb,
    int ldc, int M, int nrel) {
  __shared__ ushort st[64][136];  // half-tile stage (17 KB)
  int nwg = gridDim.x * gridDim.y;
  int lin = blockIdx.y * gridDim.x + blockIdx.x;
  int q = nwg >> 3, r8 = nwg & 7;
  int xcd = lin & 7, sub = lin >> 3;
  int swz = (xcd < r8) ? (xcd * (q + 1) + sub) : (r8 * (q + 1) + (xcd - r8) * q + sub);
  int bx = swz % gridDim.x;
  int by = swz / gridDim.x;

  const int bm = by * 128;
  const int tid = threadIdx.x, w = tid >> 6, lane = tid & 63;
  const int wr = (w >> 1) * 64, wc = (w & 1) * 64;
  const int lr = lane & 15;

  const ushort* Abh = Ah + ((size_t)(bm >> 4) + (wr >> 4)) * (K * 16) + lane * 8;
  const ushort* Abl = Al + ((size_t)(bm >> 4) + (wr >> 4)) * (K * 16) + lane * 8;
  const ushort* Bbh = Bh + (size_t)bx * (128 * K) + (size_t)(wc >> 4) * (K * 16) + lane * 8;
  const ushort* Bbl = Bl + (size_t)bx * (128 * K) + (size_t)(wc >> 4) * (K * 16) + lane * 8;

  const bool isroot = (bx == nrel);
  f4 acc[4][4] = {};

  if (isroot) {
    Frags fa, fb;
    if constexpr (K == 64) {
      load_frags<K>(fa, 0, Abh, Abl, Bbh, Bbl);
      load_frags<K>(fb, 1, Abh, Abl, Bbh, Bbl);
      mfma_frags(acc, fa);
      mfma_frags(acc, fb);
    } else {
      load_frags<K>(fa, 0, Abh, Abl, Bbh, Bbl);
      load_frags<K>(fb, 1, Abh, Abl, Bbh, Bbl);
      mfma_frags(acc, fa);
      load_frags<K>(fa, 2, Abh, Abl, Bbh, Bbl);
      mfma_frags(acc, fb);
      load_frags<K>(fb, 3, Abh, Abl, Bbh, Bbl);
      mfma_frags(acc, fa);
      mfma_frags(acc, fb);
    }
  } else {
    // 1-term: ah x bh only
#pragma unroll
    for (int ks = 0; ks < K / 32; ++ks) {
      bf8 a[4], b[4];
#pragma unroll
      for (int m = 0; m < 4; ++m)
        a[m] = *(const bf8*)(Abh + (size_t)m * (K * 16) + ks * 512);
#pragma unroll
      for (int n = 0; n < 4; ++n)
        b[n] = *(const bf8*)(Bbh + (size_t)n * (K * 16) + ks * 512);
#pragma unroll
      for (int m = 0; m < 4; ++m)
#pragma unroll
        for (int n = 0; n < 4; ++n)
          acc[m][n] = __builtin_amdgcn_mfma_f32_16x16x32_bf16(a[m], b[n], acc[m][n], 0, 0, 0);
    }
  }

  const int rgrp = (lane >> 4) * 4;
  if (isroot) {
#pragma unroll
    for (int n = 0; n < 4; ++n) {
      int col = wc + n * 16 + lr;
      float bv = bias[col];
#pragma unroll
      for (int m = 0; m < 4; ++m) {
        int r0 = bm + wr + m * 16 + rgrp;
#pragma unroll
        for (int j = 0; j < 4; ++j) {
          int r = r0 + j;
          if (r < M) Cf[(size_t)r * 128 + col] = acc[m][n][j] + bv;
        }
      }
    }
  } else {
    // two half-tile phases through 64-row LDS stage
#pragma unroll
    for (int half = 0; half < 2; ++half) {
      __syncthreads();
      if ((wr >> 6) == half) {
#pragma unroll
        for (int n = 0; n < 4; ++n) {
          int col = wc + n * 16 + lr;
#pragma unroll
          for (int m = 0; m < 4; ++m) {
            int r0 = m * 16 + rgrp;
#pragma unroll
            for (int j = 0; j < 4; ++j) st[r0 + j][col] = f2bf(acc[m][n][j]);
          }
        }
      }
      __syncthreads();
      const int rr = tid >> 4;
      const int cc = (tid & 15) * 8;
#pragma unroll
      for (int it = 0; it < 4; ++it) {
        int row = it * 16 + rr;
        int grow = bm + half * 64 + row;
        if (grow < M) {
          bf8 v = *(const bf8*)&st[row][cc];
          *(bf8*)(Cb + (size_t)grow * ldc + bx * 128 + cc) = v;
        }
      }
    }
  }
}

// ---------------- fused: mean-aggregate + root + LN + ReLU + residual + split
__global__ __launch_bounds__(256) void agg_ln(
    const int* __restrict__ pkd, const float* __restrict__ wsc,
    const int* __restrict__ rowstart, const ushort* __restrict__ T,
    const float* __restrict__ OUT, float* __restrict__ h,
    const float* __restrict__ g, const float* __restrict__ b,
    ushort* __restrict__ dh, ushort* __restrict__ dl, int writeSplit) {
  __shared__ ushort sh[2048], sl[2048];
  const int grp = blockIdx.x;
  const int w = threadIdx.x >> 6, lane = threadIdx.x & 63;
  const int lo = lane * 2;
  float2 gg = *(const float2*)(g + lo);
  float2 bb = *(const float2*)(b + lo);
  constexpr int TW = NREL * HID;
#pragma unroll
  for (int p4 = 0; p4 < 4; ++p4) {
    int r = w * 4 + p4;
    int node = grp * 16 + r;
    float2 rt = *(const float2*)(OUT + (size_t)node * HID + lo);
    float ax = 0.f, ay = 0.f;
    int e0 = rowstart[node], e1 = rowstart[node + 1];
    int p = e0;
    constexpr int U = 8;
    for (; p + U <= e1; p += U) {
      int pk[U];
      float wg[U];
      uint v[U];
#pragma unroll
      for (int u = 0; u < U; ++u) {
        pk[u] = pkd[p + u];
        wg[u] = wsc[p + u];
      }
#pragma unroll
      for (int u = 0; u < U; ++u)
        v[u] = *(const uint*)(T + (size_t)(pk[u] >> 4) * TW + (pk[u] & 15) * HID + lo);
#pragma unroll
      for (int u = 0; u < U; ++u) {
        ax += wg[u] * bf2f((ushort)(v[u] & 0xffffu));
        ay += wg[u] * bf2f((ushort)(v[u] >> 16));
      }
    }
    for (; p < e1; ++p) {
      int pk = pkd[p];
      float wg = wsc[p];
      uint v = *(const uint*)(T + (size_t)(pk >> 4) * TW + (pk & 15) * HID + lo);
      ax += wg * bf2f((ushort)(v & 0xffffu));
      ay += wg * bf2f((ushort)(v >> 16));
    }
    float vx = rt.x + ax, vy = rt.y + ay;
    float s = vx + vy, sq = vx * vx + vy * vy;
#pragma unroll
    for (int off = 32; off; off >>= 1) {
      s += __shfl_xor(s, off);
      sq += __shfl_xor(sq, off);
    }
    float mu = s * (1.f / HID);
    float var = sq * (1.f / HID) - mu * mu;
    float rs = rsqrtf(var + LN_EPS);
    float2 rr2 = *(const float2*)(h + (size_t)node * HID + lo);
    float y0 = fmaxf((vx - mu) * rs * gg.x + bb.x, 0.f) + rr2.x;
    float y1 = fmaxf((vy - mu) * rs * gg.y + bb.y, 0.f) + rr2.y;
    *(float2*)(h + (size_t)node * HID + lo) = make_float2(y0, y1);
    int off2 = (lo >> 3) * 128 + r * 8 + (lo & 7);
    ushort h0 = f2bf(y0), h1 = f2bf(y1);
    *(uint*)(sh + off2) = (uint)h0 | ((uint)h1 << 16);
    *(uint*)(sl + off2) = (uint)f2bf(y0 - bf2f(h0)) | ((uint)f2bf(y1 - bf2f(h1)) << 16);
  }
  __syncthreads();
  if (writeSplit) {
    size_t base = (size_t)grp * 2048;
    int t8 = threadIdx.x * 8;
    *(bf8*)(dh + base + t8) = *(const bf8*)(sh + t8);
    *(bf8*)(dl + base + t8) = *(const bf8*)(sl + t8);
  }
}

// ---------------------------- fallback (G<NREL): separate aggregate + LN
__global__ __launch_bounds__(256) void aggregate(
    const int* __restrict__ pkd, const float* __restrict__ wsc,
    const int* __restrict__ rowstart, const ushort* __restrict__ T,
    float* __restrict__ OUT, int r0, int G) {
  int node = blockIdx.x * 4 + (threadIdx.x >> 6);
  if (node >= NN) return;
  int lane = threadIdx.x & 63;
  int e0 = rowstart[node], e1 = rowstart[node + 1];
  const int TW = G * HID;
  const int lo = lane * 2;
  float ax = 0.f, ay = 0.f;
  int p = e0;
  constexpr int U = 8;
  for (; p + U <= e1; p += U) {
    int pk[U];
    float wg[U];
    size_t ad[U];
#pragma unroll
    for (int u = 0; u < U; ++u) {
      pk[u] = pkd[p + u];
      wg[u] = wsc[p + u];
    }
#pragma unroll
    for (int u = 0; u < U; ++u) {
      int t = (pk[u] & 15) - r0;
      bool ok = (unsigned)t < (unsigned)G;
      ad[u] = ok ? ((size_t)(pk[u] >> 4) * TW + t * HID) : 0;
      if (!ok) wg[u] = 0.f;
    }
    uint v[U];
#pragma unroll
    for (int u = 0; u < U; ++u) v[u] = *(const uint*)(T + ad[u] + lo);
#pragma unroll
    for (int u = 0; u < U; ++u) {
      ax += wg[u] * bf2f((ushort)(v[u] & 0xffffu));
      ay += wg[u] * bf2f((ushort)(v[u] >> 16));
    }
  }
  for (; p < e1; ++p) {
    int pk = pkd[p];
    float wg = wsc[p];
    int t = (pk & 15) - r0;
    if ((unsigned)t < (unsigned)G) {
      uint v = *(const uint*)(T + (size_t)(pk >> 4) * TW + t * HID + lo);
      ax += wg * bf2f((ushort)(v & 0xffffu));
      ay += wg * bf2f((ushort)(v >> 16));
    }
  }
  float2* o = (float2*)(OUT + (size_t)node * HID + lo);
  float2 cur = *o;
  cur.x += ax;
  cur.y += ay;
  *o = cur;
}

__global__ __launch_bounds__(256) void ln_relu_res_frag(
    const float* __restrict__ OUT, float* __restrict__ h,
    const float* __restrict__ g, const float* __restrict__ b,
    ushort* __restrict__ dh, ushort* __restrict__ dl) {
  __shared__ ushort sh[2048], sl[2048];
  int grp = blockIdx.x;
  int w = threadIdx.x >> 6, lane = threadIdx.x & 63;
  float2 gg = *(const float2*)(g + lane * 2);
  float2 bb = *(const float2*)(b + lane * 2);
#pragma unroll
  for (int p = 0; p < 4; ++p) {
    int r = w * 4 + p;
    int node = grp * 16 + r;
    float2 v = *(const float2*)(OUT + (size_t)node * HID + lane * 2);
    float s = v.x + v.y, sq = v.x * v.x + v.y * v.y;
#pragma unroll
    for (int off = 32; off; off >>= 1) {
      s += __shfl_xor(s, off);
      sq += __shfl_xor(sq, off);
    }
    float mu = s * (1.f / HID);
    float var = sq * (1.f / HID) - mu * mu;
    float rs = rsqrtf(var + LN_EPS);
    float2 rr = *(const float2*)(h + (size_t)node * HID + lane * 2);
    float y0 = fmaxf((v.x - mu) * rs * gg.x + bb.x, 0.f) + rr.x;
    float y1 = fmaxf((v.y - mu) * rs * gg.y + bb.y, 0.f) + rr.y;
    *(float2*)(h + (size_t)node * HID + lane * 2) = make_float2(y0, y1);
    int d = lane * 2;
    int off2 = (d >> 3) * 128 + r * 8 + (d & 7);
    ushort h0 = f2bf(y0), h1 = f2bf(y1);
    *(uint*)(sh + off2) = (uint)h0 | ((uint)h1 << 16);
    *(uint*)(sl + off2) = (uint)f2bf(y0 - bf2f(h0)) | ((uint)f2bf(y1 - bf2f(h1)) << 16);
  }
  __syncthreads();
  size_t base = (size_t)grp * 2048;
  int t8 = threadIdx.x * 8;
  *(bf8*)(dh + base + t8) = *(const bf8*)(sh + t8);
  *(bf8*)(dl + base + t8) = *(const bf8*)(sl + t8);
}

// ---------------------------------------------------------------- pooling
__global__ void pool_kernel(const float* __restrict__ h, const int* __restrict__ batch,
                            float* __restrict__ out) {
  int n0 = blockIdx.x * 64;
  if (n0 >= NN) return;
  int t = threadIdx.x;
  int nend = min(n0 + 64, NN);
  int cur = batch[n0];
  float acc = 0.f;
  for (int n = n0; n < nend; ++n) {
    int gph = batch[n];
    if (gph != cur) {
      atomicAdd(&out[cur * HID + t], acc);
      acc = 0.f;
      cur = gph;
    }
    acc += h[(size_t)n * HID + t];
  }
  atomicAdd(&out[cur * HID + t], acc);
}

// ---------------------------------------------------------------- launch
extern "C" void kernel_launch(void* const* d_in, const int* in_sizes, int n_in,
                              void* d_out, int out_size, void* d_ws, size_t ws_size,
                              hipStream_t stream) {
  const float* x = (const float*)d_in[0];
  const int* ei = (const int*)d_in[1];
  const int* et = (const int*)d_in[2];
  const int* batch = (const int*)d_in[3];
  const float* Wp = (const float*)d_in[4];
  const float* bp = (const float*)d_in[5];
  const float* rel_w = (const float*)d_in[6];
  const float* root_w = (const float*)d_in[7];
  const float* conv_b = (const float*)d_in[8];
  const float* ln_g = (const float*)d_in[9];
  const float* ln_b = (const float*)d_in[10];
  float* out = (float*)d_out;
  const int* srcv = ei;
  const int* dstv = ei + NE;

  const int NGRP = NN / 16;       // 3125
  const int NGRP_PAD = NGRP + 3;  // GEMMs read up to group 3127 (stores guarded)

  char* w = (char*)d_ws;
  auto alloc = [&](size_t bytes) {
    char* p = w;
    w += (bytes + 255) & ~(size_t)255;
    return p;
  };
  float* h = (float*)alloc((size_t)NN * HID * 4);
  float* OUT = (float*)alloc((size_t)NN * HID * 4);
  float* winv = (float*)alloc((size_t)NN * NREL * 4);  // zero-span start
  int* deg = (int*)alloc((size_t)NN * 4);
  int* rowstart = (int*)alloc((size_t)(NN + 1) * 4);
  int* fillpos = (int*)alloc((size_t)NN * 4);
  char* zend = w;  // zero-span end
  int* pkd = (int*)alloc((size_t)NE * 4);
  float* wsc = (float*)alloc((size_t)NE * 4);
  int* partial = (int*)alloc(256 * 4);
  ushort* xh = (ushort*)alloc((size_t)NGRP_PAD * 1024 * 2);
  ushort* xl = (ushort*)alloc((size_t)NGRP_PAD * 1024 * 2);
  ushort* hh = (ushort*)alloc((size_t)NGRP_PAD * 2048 * 2);
  ushort* hl = (ushort*)alloc((size_t)NGRP_PAD * 2048 * 2);
  ushort* Wph = (ushort*)alloc((size_t)IND * HID * 2);
  ushort* Wpl = (ushort*)alloc((size_t)IND * HID * 2);
  ushort* Relh = (ushort*)alloc((size_t)NLAY * NMAT * HID * HID * 2);
  ushort* Rell = (ushort*)alloc((size_t)NLAY * NMAT * HID * HID * 2);

  size_t used = (size_t)(w - (char*)d_ws);
  size_t rem = (ws_size > used) ? ws_size - used : 0;
  int G = 1;
  if (rem >= (size_t)NN * 10 * HID * 2) G = 10;
  else if (rem >= (size_t)NN * 5 * HID * 2) G = 5;
  else if (rem >= (size_t)NN * 2 * HID * 2) G = 2;
  ushort* T = (ushort*)alloc((size_t)NN * G * HID * 2);
  const int P = NREL / G;

  const int NB_E = (NE + 255) / 256;
  const int NB_N = (NN + 255) / 256;
  const int MB = (NN + 127) / 128;  // 391
  const int ZSPAN = (int)((zend - (char*)winv) / 4);

  zero_kernel<<<dim3(1024), dim3(256), 0, stream>>>(winv, ZSPAN);
  zero_kernel<<<dim3(32), dim3(256), 0, stream>>>(out, NG * HID);

  count_edges<<<dim3(NB_E), dim3(256), 0, stream>>>(dstv, et, winv, deg);
  invert_winv<<<dim3((NN * NREL + 255) / 256), dim3(256), 0, stream>>>(winv);
  scan_block<<<dim3(NB_N), dim3(256), 0, stream>>>(deg, rowstart, partial);
  scan_partials<<<dim3(1), dim3(256), 0, stream>>>(partial, NB_N);
  scan_add<<<dim3(NB_N), dim3(256), 0, stream>>>(rowstart, partial);
  fill_csr<<<dim3(NB_E), dim3(256), 0, stream>>>(dstv, srcv, et, fillpos, rowstart,
                                                 winv, pkd, wsc);

  transpose_split_frag<<<dim3((IND * HID + 255) / 256), dim3(256), 0, stream>>>(
      Wp, Wph, Wpl, 1, IND, 1, 1, 0);
  transpose_split_frag<<<dim3((NLAY * NREL * HID * HID + 255) / 256), dim3(256), 0, stream>>>(
      rel_w, Relh, Rell, NLAY * NREL, HID, NREL, NMAT, 0);
  transpose_split_frag<<<dim3((NLAY * HID * HID + 255) / 256), dim3(256), 0, stream>>>(
      root_w, Relh, Rell, NLAY, HID, 1, NMAT, NREL);

  split_frag<IND><<<dim3(NGRP), dim3(256), 0, stream>>>(x, xh, xl);

  // projection: h = x @ Wp + bp  (grid x=1, nrel=0 -> root 3-term path)
  gemm_frag<IND><<<dim3(1, MB), dim3(256), 0, stream>>>(
      xh, xl, Wph, Wpl, bp, h, (ushort*)nullptr, 128, NN, 0);
  split_frag<HID><<<dim3(NGRP), dim3(256), 0, stream>>>(h, hh, hl);

  for (int l = 0; l < NLAY; ++l) {
    const ushort* Bh = Relh + (size_t)l * NMAT * HID * HID;
    const ushort* Bl = Rell + (size_t)l * NMAT * HID * HID;
    if (G == NREL) {
      gemm_frag<HID><<<dim3(NREL + 1, MB), dim3(256), 0, stream>>>(
          hh, hl, Bh, Bl, conv_b + (size_t)l * HID, OUT, T, G * HID, NN, NREL);
      agg_ln<<<dim3(NGRP), dim3(256), 0, stream>>>(
          pkd, wsc, rowstart, T, OUT, h, ln_g + (size_t)l * HID, ln_b + (size_t)l * HID,
          hh, hl, (l != NLAY - 1) ? 1 : 0);
    } else {
      gemm_frag<HID><<<dim3(1, MB), dim3(256), 0, stream>>>(
          hh, hl, Bh + (size_t)NREL * HID * HID, Bl + (size_t)NREL * HID * HID,
          conv_b + (size_t)l * HID, OUT, (ushort*)nullptr, 128, NN, 0);
      for (int p = 0; p < P; ++p) {
        gemm_frag<HID><<<dim3(G, MB), dim3(256), 0, stream>>>(
            hh, hl, Bh + (size_t)p * G * HID * HID, Bl + (size_t)p * G * HID * HID,
            (const float*)nullptr, (float*)nullptr, T, G * HID, NN, -1);
        aggregate<<<dim3(NN / 4), dim3(256), 0, stream>>>(pkd, wsc, rowstart, T, OUT,
                                                          p * G, G);
      }
      ln_relu_res_frag<<<dim3(NGRP), dim3(256), 0, stream>>>(
          OUT, h, ln_g + (size_t)l * HID, ln_b + (size_t)l * HID, hh, hl);
    }
  }

  pool_kernel<<<dim3((NN + 63) / 64), dim3(128), 0, stream>>>(h, batch, out);
}